// Round 3
// baseline (463.240 us; speedup 1.0000x reference)
//
#include <hip/hip_runtime.h>

// Problem constants: B=16, C_img=3, H=448, W=1024.
#define BB 16
#define HH 448
#define WW 1024
constexpr int HW      = HH * WW;           // 458752
constexpr int TOTAL   = BB * HW;           // 7340032
constexpr int RPT     = 4;                 // rows per block (tile height)
constexpr int TILES_Y = HH / RPT;          // 112
constexpr int NBLK    = BB * TILES_Y;      // 1792
constexpr int NTHR    = 256;               // 256 thr * 4 px = one full row

struct Flow5 { float u[5], v[5]; };

// Load one row's flow inputs (float4 per thread + right-neighbor scalars),
// compute the flow sample. If OWN, also accumulate EPE and -logvar/2 terms.
template <bool OWN>
__device__ __forceinline__ void load_row(
    const float* __restrict__ mean, const float* __restrict__ lv,
    const float* __restrict__ eps,  const float* __restrict__ target,
    int base, bool hr, Flow5& f, float& se, float& sp)
{
    const float4 m0 = *(const float4*)(mean + base);
    const float4 m1 = *(const float4*)(mean + base + HW);
    const float4 l0 = *(const float4*)(lv   + base);
    const float4 l1 = *(const float4*)(lv   + base + HW);
    const float4 e0 = *(const float4*)(eps  + base);
    const float4 e1 = *(const float4*)(eps  + base + HW);

    float m0r = 0.f, m1r = 0.f, l0r = 0.f, l1r = 0.f, e0r = 0.f, e1r = 0.f;
    if (hr) {   // right-neighbor scalars: same/adjacent cache line, L1-hot
        m0r = mean[base + 4]; m1r = mean[base + HW + 4];
        l0r = lv[base + 4];   l1r = lv[base + HW + 4];
        e0r = eps[base + 4];  e1r = eps[base + HW + 4];
    }

    const float* M0 = &m0.x; const float* M1 = &m1.x;
    const float* L0 = &l0.x; const float* L1 = &l1.x;
    const float* E0 = &e0.x; const float* E1 = &e1.x;
    #pragma unroll
    for (int j = 0; j < 4; ++j) {
        f.u[j] = M0[j] + __expf(0.5f * L0[j]) * E0[j];
        f.v[j] = M1[j] + __expf(0.5f * L1[j]) * E1[j];
    }
    f.u[4] = m0r + __expf(0.5f * l0r) * e0r;
    f.v[4] = m1r + __expf(0.5f * l1r) * e1r;

    if (OWN) {
        const float4 t0 = *(const float4*)(target + base);
        const float4 t1 = *(const float4*)(target + base + HW);
        const float* T0 = &t0.x; const float* T1 = &t1.x;
        #pragma unroll
        for (int j = 0; j < 4; ++j) {
            const float du = M0[j] - T0[j];
            const float dv = M1[j] - T1[j];
            sp += sqrtf(du * du + dv * dv);
            se -= 0.5f * (L0[j] + L1[j]);
        }
    }
}

__device__ __forceinline__ void process_row(
    const float* __restrict__ img1, const float* __restrict__ img2,
    int b3, int y, int x, bool hr, bool has_d,
    const Flow5& cur, const Flow5& nxt, float& se)
{
    const int r = y * WW + x;
    const float4 c0 = *(const float4*)(img1 + b3 + r);
    const float4 c1 = *(const float4*)(img1 + b3 + HW + r);
    const float4 c2 = *(const float4*)(img1 + b3 + 2 * HW + r);
    const float* I1[3] = { &c0.x, &c1.x, &c2.x };

    #pragma unroll
    for (int j = 0; j < 4; ++j) {
        // smoothness
        float dx2 = 0.f, dy2 = 0.f;
        if (j < 3 || hr) {
            const float a = cur.u[j + 1] - cur.u[j];
            const float c = cur.v[j + 1] - cur.v[j];
            dx2 = a * a + c * c;
        }
        if (has_d) {
            const float a = nxt.u[j] - cur.u[j];
            const float c = nxt.v[j] - cur.v[j];
            dy2 = a * a + c * c;
        }
        const float smooth = sqrtf(dx2 + dy2 + 1e-5f);

        // bilinear warp of img2
        const float xs = (float)(x + j) + cur.u[j];
        const float ys = (float)y + cur.v[j];
        const float x0f = floorf(xs), y0f = floorf(ys);
        const float wx = xs - x0f,    wy = ys - y0f;
        int x0 = min(max((int)x0f, 0), WW - 1);
        const int x1 = min(x0 + 1, WW - 1);
        int y0 = min(max((int)y0f, 0), HH - 1);
        const int y1 = min(y0 + 1, HH - 1);
        const int i00 = y0 * WW + x0, i01 = y0 * WW + x1;
        const int i10 = y1 * WW + x0, i11 = y1 * WW + x1;

        float A = 0.f;
        #pragma unroll
        for (int c = 0; c < 3; ++c) {
            const int o = b3 + c * HW;
            const float v00 = img2[o + i00];
            const float v01 = img2[o + i01];
            const float v10 = img2[o + i10];
            const float v11 = img2[o + i11];
            const float top = v00 + wx * (v01 - v00);
            const float bot = v10 + wx * (v11 - v10);
            const float w   = top + wy * (bot - top);
            const float d   = I1[c][j] - w;
            A += d * d;
        }
        se += smooth + sqrtf(A + 1e-5f);
    }
}

__global__ __launch_bounds__(NTHR) void elbo_main(
    const float* __restrict__ mean, const float* __restrict__ lv,
    const float* __restrict__ img1, const float* __restrict__ img2,
    const float* __restrict__ target, const float* __restrict__ eps,
    float2* __restrict__ partials)
{
    const int blk = blockIdx.x;
    const int b   = blk / TILES_Y;
    const int ty  = blk - b * TILES_Y;
    const int y0  = ty * RPT;
    const int x   = (int)threadIdx.x * 4;
    const bool hr = (x + 4 < WW);
    const int base_b = b * 2 * HW;
    const int b3     = b * 3 * HW;

    float se = 0.f, sp = 0.f;

    Flow5 cur;
    load_row<true>(mean, lv, eps, target, base_b + y0 * WW + x, hr, cur, se, sp);

    #pragma unroll
    for (int i = 0; i < RPT; ++i) {
        const int y = y0 + i;
        const bool has_d = (y + 1 < HH);
        Flow5 nxt = {};
        if (i < RPT - 1) {
            load_row<true>(mean, lv, eps, target,
                           base_b + (y + 1) * WW + x, hr, nxt, se, sp);
        } else if (has_d) {
            load_row<false>(mean, lv, eps, target,
                            base_b + (y + 1) * WW + x, hr, nxt, se, sp);
        }
        process_row(img1, img2, b3, y, x, hr, has_d, cur, nxt, se);
        cur = nxt;
    }

    // ---- block reduction ----
    #pragma unroll
    for (int off = 32; off > 0; off >>= 1) {
        se += __shfl_down(se, off);
        sp += __shfl_down(sp, off);
    }
    __shared__ float s_e[NTHR / 64], s_p[NTHR / 64];
    const int lane = threadIdx.x & 63;
    const int wid  = threadIdx.x >> 6;
    if (lane == 0) { s_e[wid] = se; s_p[wid] = sp; }
    __syncthreads();
    if (threadIdx.x == 0) {
        float te = 0.f, tp = 0.f;
        #pragma unroll
        for (int i = 0; i < NTHR / 64; ++i) { te += s_e[i]; tp += s_p[i]; }
        partials[blockIdx.x] = make_float2(te, tp);
    }
}

__global__ __launch_bounds__(256) void elbo_final(
    const float2* __restrict__ partials, float* __restrict__ out)
{
    double se = 0.0, sp = 0.0;
    for (int i = threadIdx.x; i < NBLK; i += 256) {
        const float2 v = partials[i];
        se += (double)v.x;
        sp += (double)v.y;
    }
    #pragma unroll
    for (int off = 32; off > 0; off >>= 1) {
        se += __shfl_down(se, off);
        sp += __shfl_down(sp, off);
    }
    __shared__ double s_e[4], s_p[4];
    const int lane = threadIdx.x & 63;
    const int wid  = threadIdx.x >> 6;
    if (lane == 0) { s_e[wid] = se; s_p[wid] = sp; }
    __syncthreads();
    if (threadIdx.x == 0) {
        double te = 0.0, tp = 0.0;
        #pragma unroll
        for (int i = 0; i < 4; ++i) { te += s_e[i]; tp += s_p[i]; }
        out[0] = (float)(te / (double)BB);
        out[1] = (float)(tp / (double)TOTAL);
    }
}

extern "C" void kernel_launch(void* const* d_in, const int* in_sizes, int n_in,
                              void* d_out, int out_size, void* d_ws, size_t ws_size,
                              hipStream_t stream) {
    const float* mean   = (const float*)d_in[0];
    const float* logvar = (const float*)d_in[1];
    const float* img1   = (const float*)d_in[2];
    const float* img2   = (const float*)d_in[3];
    const float* target = (const float*)d_in[4];
    const float* eps    = (const float*)d_in[5];
    float* out = (float*)d_out;
    float2* partials = (float2*)d_ws;   // NBLK * 8 B = 14 KiB

    elbo_main<<<NBLK, NTHR, 0, stream>>>(mean, logvar, img1, img2, target, eps, partials);
    elbo_final<<<1, 256, 0, stream>>>(partials, out);
}